// Round 13
// baseline (756.501 us; speedup 1.0000x reference)
//
#include <hip/hip_runtime.h>

#define N_NODES 50000
#define N_EDGES 800000
#define DD 128
#define HH 128
#define LL 4
#define AHH 16
#define LN_EPS 1e-5f
#define NCOLS 432   // 128 S | 128 P1 | 128 Pd | 16 SA | 16 P1A | 16 PdA
#define PDXW 160    // PdX row: 128 Pd + 16 PdA + 16 pad (320B, line-aligned)
#define SCAN_B 512
#define SCAN_NB ((N_NODES + SCAN_B - 1) / SCAN_B)
#define WTPAD 136
#define WT_BLOCKS ((LL*NCOLS*DD)/256)   // 864, exact

typedef unsigned short u16;
typedef unsigned int u32;
typedef __attribute__((ext_vector_type(8))) short short8;
typedef __attribute__((ext_vector_type(4))) float f32x4;

__device__ __forceinline__ float bf2f(u16 h){
  u32 u = ((u32)h) << 16;
  return __builtin_bit_cast(float, u);
}
__device__ __forceinline__ float bflo(u32 v){ return __builtin_bit_cast(float, v << 16); }
__device__ __forceinline__ float bfhi(u32 v){ return __builtin_bit_cast(float, v & 0xffff0000u); }
__device__ __forceinline__ u16 f2bf(float x){
  u32 u = __builtin_bit_cast(u32, x);
  u += 0x7fffu + ((u >> 16) & 1u);
  return (u16)(u >> 16);
}

// ---------------- sentinel (workspace too small) ----------------
__global__ void k_fail(float* out){
  int i = blockIdx.x*256 + threadIdx.x;
  if (i < N_NODES*2) out[i] = 1.0e6f;
}

// ---------------- fused: f32->bf16 conversion + degree histograms ----------------
__global__ __launch_bounds__(256) void k_cvt_hist(const float* __restrict__ X,
    u16* __restrict__ Xb, const int* __restrict__ ei, int* degO, int* degI){
  int i = blockIdx.x*256 + threadIdx.x;
  if (i < N_NODES*DD) Xb[i] = f2bf(X[i]);
  if (i < N_EDGES){
    atomicAdd(&degO[ei[N_EDGES + i]], 1);  // tgt histogram (outgoing view)
    atomicAdd(&degI[ei[i]], 1);            // src histogram (incoming view)
  }
}

// 3-phase parallel exclusive scan
__global__ __launch_bounds__(SCAN_B) void k_scan1(const int* __restrict__ degO,
                                                  const int* __restrict__ degI, int* bsum){
  int b = blockIdx.x, t = threadIdx.x;
  const int* deg = blockIdx.y ? degI : degO;
  int i = b*SCAN_B + t;
  int v = (i < N_NODES) ? deg[i] : 0;
  #pragma unroll
  for (int m = 1; m < 64; m <<= 1) v += __shfl_xor(v, m);
  __shared__ int ws[SCAN_B/64];
  if ((t & 63) == 0) ws[t >> 6] = v;
  __syncthreads();
  if (t == 0){
    int s = 0;
    for (int w = 0; w < SCAN_B/64; ++w) s += ws[w];
    bsum[blockIdx.y*SCAN_NB + b] = s;
  }
}
__global__ void k_scan2(int* bsum, int* offO, int* offI){
  if (threadIdx.x == 0){
    int run = 0;
    for (int i = 0; i < SCAN_NB; ++i){ int v = bsum[i]; bsum[i] = run; run += v; }
    offO[N_NODES] = run;
    run = 0;
    for (int i = 0; i < SCAN_NB; ++i){ int v = bsum[SCAN_NB+i]; bsum[SCAN_NB+i] = run; run += v; }
    offI[N_NODES] = run;
  }
}
__global__ __launch_bounds__(SCAN_B) void k_scan3(const int* __restrict__ degO,
                                                  const int* __restrict__ degI,
                                                  const int* __restrict__ bsum,
                                                  int* offO, int* offI){
  int b = blockIdx.x, t = threadIdx.x, lane = t & 63, w = t >> 6;
  const int* deg = blockIdx.y ? degI : degO;
  int* off = blockIdx.y ? offI : offO;
  int i = b*SCAN_B + t;
  int v = (i < N_NODES) ? deg[i] : 0;
  int x = v;
  #pragma unroll
  for (int m = 1; m < 64; m <<= 1){ int tt = __shfl_up(x, m); if (lane >= m) x += tt; }
  __shared__ int ws[SCAN_B/64];
  if (lane == 63) ws[w] = x;
  __syncthreads();
  int woff = 0;
  for (int k = 0; k < w; ++k) woff += ws[k];
  if (i < N_NODES) off[i] = bsum[blockIdx.y*SCAN_NB + b] + woff + x - v;
}

__global__ void k_scatter(const int* __restrict__ ei, const int* __restrict__ offO,
                          const int* __restrict__ offI, int* cursO, int* cursI,
                          int* csrO, int* csrI){
  int e = blockIdx.x*256 + threadIdx.x;
  if (e >= N_EDGES) return;
  int s = ei[e], t = ei[N_EDGES + e];
  int p = atomicAdd(&cursO[t], 1); csrO[offO[t] + p] = s;
  int q = atomicAdd(&cursI[s], 1); csrI[offI[s] + q] = t;
}

// ---------------- fused weight+bias packing (f32 sources -> bf16 WT, f32 bsA/bcA) ----------------
__global__ void k_pack(const float* __restrict__ Wself, const float* __restrict__ Wctx,
                       const float* __restrict__ A1, const float* __restrict__ bs,
                       const float* __restrict__ bc, u16* __restrict__ WT,
                       float* bsA, float* bcA){
  if (blockIdx.x == WT_BLOCKS){
    int i = threadIdx.x;
    if (i < LL*2*AHH){
      int l = i >> 5, which = (i >> 4) & 1, a = i & 15;
      const float* b = which ? (bc + l*HH) : (bs + l*HH);
      const float* A = A1 + (size_t)l*HH*AHH;
      float v = 0.f;
      for (int h = 0; h < HH; ++h) v += b[h] * A[h*AHH + a];
      (which ? bcA : bsA)[l*AHH + a] = v;
    }
    return;
  }
  int idx = blockIdx.x*256 + threadIdx.x;
  int k = idx & 127;
  int j = (idx >> 7) % NCOLS;
  int l = idx / (NCOLS*DD);
  const float* Ws = Wself + (size_t)l*DD*HH;
  const float* Wc = Wctx + (size_t)l*2*DD*HH;
  const float* A  = A1 + (size_t)l*HH*AHH;
  float v = 0.f;
  if (j < 128) v = Ws[k*HH + j];
  else if (j < 256) v = Wc[k*HH + (j-128)];
  else if (j < 384) v = Wc[(128+k)*HH + (j-256)] - Wc[k*HH + (j-256)];
  else if (j < 400){ int a = j-384; for (int h=0; h<HH; ++h) v += Ws[k*HH+h] * A[h*AHH+a]; }
  else if (j < 416){ int a = j-400; for (int h=0; h<HH; ++h) v += Wc[k*HH+h] * A[h*AHH+a]; }
  else { int a = j-416; for (int h=0; h<HH; ++h) v += (Wc[(128+k)*HH+h] - Wc[k*HH+h]) * A[h*AHH+a]; }
  WT[((size_t)l*NCOLS + j)*DD + k] = f2bf(v);
}

// ---------------- fused GEMM: 3-tile LDS staging + transposed-C epilogue ----------------
// mfma operand order swapped (WT fragment first): C's lane&15 dim = node,
// quad*4+r dim = WT col -> each lane's 4 acc regs are 4 consecutive output
// cols -> one 8B uint2 store per j (27 stores vs 108 short-stores), branch-free.
struct GemmOut { u16 *S, *P1, *PdX, *SA, *P1A; };

__global__ __launch_bounds__(256) void k_gemm(const u16* __restrict__ X,
                                              const u16* __restrict__ WT, GemmOut o){
  __shared__ u16 lw[3*16*WTPAD];
  int tid = threadIdx.x;
  int wid = tid >> 6, lane = tid & 63;
  int m0 = (blockIdx.x*4 + wid)*16;
  bool mvalid = (m0 < N_NODES);
  int m0c = mvalid ? m0 : (N_NODES - 16);
  int l15 = lane & 15, quad = lane >> 4;
  int sr = tid >> 4, sp = tid & 15;

  f32x4 acc[27];
  #pragma unroll
  for (int j = 0; j < 27; ++j) acc[j] = (f32x4){0.f,0.f,0.f,0.f};

  const u16* xr = X + (size_t)(m0c + l15)*DD + quad*8;
  short8 a[4];
  #pragma unroll
  for (int ks = 0; ks < 4; ++ks) a[ks] = *(const short8*)(xr + ks*32);

  short8 st[3];
  #pragma unroll
  for (int k = 0; k < 3; ++k)
    st[k] = *(const short8*)(WT + ((size_t)k*16 + sr)*DD + sp*8);

  for (int stage = 0; stage < 9; ++stage){
    int jbase = stage*3;
    __syncthreads();
    #pragma unroll
    for (int k = 0; k < 3; ++k)
      *(short8*)(&lw[(k*16 + sr)*WTPAD + sp*8]) = st[k];
    __syncthreads();
    if (stage < 8){
      #pragma unroll
      for (int k = 0; k < 3; ++k)
        st[k] = *(const short8*)(WT + ((size_t)(jbase+3+k)*16 + sr)*DD + sp*8);
    }
    #pragma unroll
    for (int k = 0; k < 3; ++k){
      const u16* wb = &lw[(k*16 + l15)*WTPAD + quad*8];
      #pragma unroll
      for (int ks = 0; ks < 4; ++ks){
        short8 b = *(const short8*)(wb + ks*32);
        acc[jbase+k] = __builtin_amdgcn_mfma_f32_16x16x32_bf16(b, a[ks], acc[jbase+k], 0, 0, 0);
      }
    }
  }
  if (!mvalid) return;
  int node = m0 + l15;
  #pragma unroll
  for (int j = 0; j < 27; ++j){
    uint2 pk;
    pk.x = (u32)f2bf(acc[j][0]) | ((u32)f2bf(acc[j][1]) << 16);
    pk.y = (u32)f2bf(acc[j][2]) | ((u32)f2bf(acc[j][3]) << 16);
    int cb = j*16 + quad*4;
    if (j < 8)        *(uint2*)(o.S   + (size_t)node*128 + cb)        = pk;
    else if (j < 16)  *(uint2*)(o.P1  + (size_t)node*128 + cb - 128)  = pk;
    else if (j < 24)  *(uint2*)(o.PdX + (size_t)node*PDXW + cb - 256) = pk;
    else if (j == 24) *(uint2*)(o.SA  + (size_t)node*16 + quad*4)     = pk;
    else if (j == 25) *(uint2*)(o.P1A + (size_t)node*16 + quad*4)     = pk;
    else              *(uint2*)(o.PdX + (size_t)node*PDXW + 128 + quad*4) = pk;
  }
}

// ------- fused CSR gather (single pass over PdX rows: Pd + PdA together) -------
__global__ __launch_bounds__(256) void k_aggepi(int l,
  const u16* __restrict__ S, const u16* __restrict__ P1,
  const u16* __restrict__ PdX, const u16* __restrict__ SA,
  const u16* __restrict__ P1A,
  const int* __restrict__ offO, const int* __restrict__ offI,
  const int* __restrict__ csrO, const int* __restrict__ csrI,
  const float* __restrict__ b_self, const float* __restrict__ b_ctx,
  const float* __restrict__ bsA, const float* __restrict__ bcA,
  const float* __restrict__ att_b1, const float* __restrict__ att_w2,
  const float* __restrict__ gamma, const float* __restrict__ beta,
  const float* __restrict__ flog,
  u16* __restrict__ xb16,
  const float* __restrict__ clsW, const float* __restrict__ clsB,
  float* __restrict__ out)
{
  int n = (blockIdx.x * 256 + threadIdx.x) >> 6;
  int lane = threadIdx.x & 63;
  int f0 = lane * 2;
  const u16* PdF  = PdX + f0;                    // main: u32 @ PdF + nb*PDXW (2 feats/lane)
  const u16* PdAF = PdX + 128 + (lane & 7)*2;    // aux: u32 @ PdAF + nb*PDXW (PdA pair, replicated x8)

  int begO = offO[n], endO = offO[n+1];
  int begI = offI[n], endI = offI[n+1];

  float o00=0.f,o01=0.f,o10=0.f,o11=0.f,o20=0.f,o21=0.f,o30=0.f,o31=0.f;
  float i00=0.f,i01=0.f,i10=0.f,i11=0.f,i20=0.f,i21=0.f,i30=0.f,i31=0.f;
  float poa0=0.f, poa1=0.f, pia0=0.f, pia1=0.f;  // PdA pair sums (feat 2p, 2p+1), p = lane&7

  int eO = begO, eI = begI;
  // alignment heads (csr bases 256B-aligned)
  for (; eO < endO && (eO & 3); ++eO){
    size_t rb = (size_t)csrO[eO]*PDXW;
    u32 v = *(const u32*)(PdF + rb);
    u32 p = *(const u32*)(PdAF + rb);
    o00 += bflo(v); o01 += bfhi(v);
    poa0 += bflo(p); poa1 += bfhi(p);
  }
  for (; eI < endI && (eI & 3); ++eI){
    size_t rb = (size_t)csrI[eI]*PDXW;
    u32 v = *(const u32*)(PdF + rb);
    u32 p = *(const u32*)(PdAF + rb);
    i00 += bflo(v); i01 += bfhi(v);
    pia0 += bflo(p); pia1 += bfhi(p);
  }
  // fused main loop: 4 O + 4 I rows (+aux) in flight, int4 index loads
  for (; eO + 4 <= endO && eI + 4 <= endI; eO += 4, eI += 4){
    int4 nO = *(const int4*)(csrO + eO);
    int4 nI = *(const int4*)(csrI + eI);
    size_t rO0 = (size_t)nO.x*PDXW, rO1 = (size_t)nO.y*PDXW, rO2 = (size_t)nO.z*PDXW, rO3 = (size_t)nO.w*PDXW;
    size_t rI0 = (size_t)nI.x*PDXW, rI1 = (size_t)nI.y*PDXW, rI2 = (size_t)nI.z*PDXW, rI3 = (size_t)nI.w*PDXW;
    u32 a0 = *(const u32*)(PdF + rO0);
    u32 a1 = *(const u32*)(PdF + rO1);
    u32 a2 = *(const u32*)(PdF + rO2);
    u32 a3 = *(const u32*)(PdF + rO3);
    u32 b0 = *(const u32*)(PdF + rI0);
    u32 b1 = *(const u32*)(PdF + rI1);
    u32 b2 = *(const u32*)(PdF + rI2);
    u32 b3 = *(const u32*)(PdF + rI3);
    u32 pa0 = *(const u32*)(PdAF + rO0);
    u32 pa1 = *(const u32*)(PdAF + rO1);
    u32 pa2 = *(const u32*)(PdAF + rO2);
    u32 pa3 = *(const u32*)(PdAF + rO3);
    u32 pb0 = *(const u32*)(PdAF + rI0);
    u32 pb1 = *(const u32*)(PdAF + rI1);
    u32 pb2 = *(const u32*)(PdAF + rI2);
    u32 pb3 = *(const u32*)(PdAF + rI3);
    o00 += bflo(a0); o01 += bfhi(a0);
    o10 += bflo(a1); o11 += bfhi(a1);
    o20 += bflo(a2); o21 += bfhi(a2);
    o30 += bflo(a3); o31 += bfhi(a3);
    i00 += bflo(b0); i01 += bfhi(b0);
    i10 += bflo(b1); i11 += bfhi(b1);
    i20 += bflo(b2); i21 += bfhi(b2);
    i30 += bflo(b3); i31 += bfhi(b3);
    poa0 += bflo(pa0) + bflo(pa1) + bflo(pa2) + bflo(pa3);
    poa1 += bfhi(pa0) + bfhi(pa1) + bfhi(pa2) + bfhi(pa3);
    pia0 += bflo(pb0) + bflo(pb1) + bflo(pb2) + bflo(pb3);
    pia1 += bfhi(pb0) + bfhi(pb1) + bfhi(pb2) + bfhi(pb3);
  }
  // drain O
  for (; eO + 4 <= endO; eO += 4){
    int4 nO = *(const int4*)(csrO + eO);
    size_t rO0 = (size_t)nO.x*PDXW, rO1 = (size_t)nO.y*PDXW, rO2 = (size_t)nO.z*PDXW, rO3 = (size_t)nO.w*PDXW;
    u32 a0 = *(const u32*)(PdF + rO0);
    u32 a1 = *(const u32*)(PdF + rO1);
    u32 a2 = *(const u32*)(PdF + rO2);
    u32 a3 = *(const u32*)(PdF + rO3);
    u32 pa0 = *(const u32*)(PdAF + rO0);
    u32 pa1 = *(const u32*)(PdAF + rO1);
    u32 pa2 = *(const u32*)(PdAF + rO2);
    u32 pa3 = *(const u32*)(PdAF + rO3);
    o00 += bflo(a0); o01 += bfhi(a0);
    o10 += bflo(a1); o11 += bfhi(a1);
    o20 += bflo(a2); o21 += bfhi(a2);
    o30 += bflo(a3); o31 += bfhi(a3);
    poa0 += bflo(pa0) + bflo(pa1) + bflo(pa2) + bflo(pa3);
    poa1 += bfhi(pa0) + bfhi(pa1) + bfhi(pa2) + bfhi(pa3);
  }
  for (; eO < endO; ++eO){
    size_t rb = (size_t)csrO[eO]*PDXW;
    u32 v = *(const u32*)(PdF + rb);
    u32 p = *(const u32*)(PdAF + rb);
    o00 += bflo(v); o01 += bfhi(v);
    poa0 += bflo(p); poa1 += bfhi(p);
  }
  // drain I
  for (; eI + 4 <= endI; eI += 4){
    int4 nI = *(const int4*)(csrI + eI);
    size_t rI0 = (size_t)nI.x*PDXW, rI1 = (size_t)nI.y*PDXW, rI2 = (size_t)nI.z*PDXW, rI3 = (size_t)nI.w*PDXW;
    u32 b0 = *(const u32*)(PdF + rI0);
    u32 b1 = *(const u32*)(PdF + rI1);
    u32 b2 = *(const u32*)(PdF + rI2);
    u32 b3 = *(const u32*)(PdF + rI3);
    u32 pb0 = *(const u32*)(PdAF + rI0);
    u32 pb1 = *(const u32*)(PdAF + rI1);
    u32 pb2 = *(const u32*)(PdAF + rI2);
    u32 pb3 = *(const u32*)(PdAF + rI3);
    i00 += bflo(b0); i01 += bfhi(b0);
    i10 += bflo(b1); i11 += bfhi(b1);
    i20 += bflo(b2); i21 += bfhi(b2);
    i30 += bflo(b3); i31 += bfhi(b3);
    pia0 += bflo(pb0) + bflo(pb1) + bflo(pb2) + bflo(pb3);
    pia1 += bfhi(pb0) + bfhi(pb1) + bfhi(pb2) + bfhi(pb3);
  }
  for (; eI < endI; ++eI){
    size_t rb = (size_t)csrI[eI]*PDXW;
    u32 v = *(const u32*)(PdF + rb);
    u32 p = *(const u32*)(PdAF + rb);
    i00 += bflo(v); i01 += bfhi(v);
    pia0 += bflo(p); pia1 += bfhi(p);
  }
  float ao0 = (o00+o10)+(o20+o30), ao1 = (o01+o11)+(o21+o31);
  float ai0 = (i00+i10)+(i20+i30), ai1 = (i01+i11)+(i21+i31);

  // PdA sums: lane k holds pair (k&7) = feats 2(k&7), 2(k&7)+1 — replicated 8x.
  int a16 = lane & 15, g = lane >> 4;
  float aoa, aia;
  {
    int p = a16 >> 1;
    float t0 = __shfl(poa0, p), t1 = __shfl(poa1, p);
    float u0 = __shfl(pia0, p), u1 = __shfl(pia1, p);
    int odd = a16 & 1;
    aoa = odd ? t1 : t0;
    aia = odd ? u1 : u0;
  }

  float dO = (float)(endO - begO), dI = (float)(endI - begI);

  // --- three views, 2 features per lane ---
  u32 sv = *(const u32*)(S  + (size_t)n*128 + f0);
  u32 pv = *(const u32*)(P1 + (size_t)n*128 + f0);
  float2 bsv = *(const float2*)(b_self + l*128 + f0);
  float2 bcv = *(const float2*)(b_ctx  + l*128 + f0);
  float p10 = bflo(pv), p11 = bfhi(pv);
  float mv00 = bflo(sv) + bsv.x;
  float mv01 = bfhi(sv) + bsv.y;
  float mv10 = dO*p10 + ao0 + bcv.x, mv11 = dO*p11 + ao1 + bcv.y;
  float mv20 = dI*p10 + ai0 + bcv.x, mv21 = dI*p11 + ai1 + bcv.y;

  // --- attention: lanes [v*16 + a], v<3 compute tanh(t + b1)*w2, reduce over a ---
  int a = a16, v = g;
  float u = 0.f;
  if (v < 3){
    float t;
    if (v == 0)      t = bf2f(SA[(size_t)n*16 + a]) + bsA[l*16 + a];
    else if (v == 1) t = dO*bf2f(P1A[(size_t)n*16 + a]) + aoa + bcA[l*16 + a];
    else             t = dI*bf2f(P1A[(size_t)n*16 + a]) + aia + bcA[l*16 + a];
    u = tanhf(t + att_b1[l*16 + a]) * att_w2[l*16 + a];
  }
  u += __shfl_xor(u, 1); u += __shfl_xor(u, 2);
  u += __shfl_xor(u, 4); u += __shfl_xor(u, 8);
  float s0 = __shfl(u, 0), s1 = __shfl(u, 16), s2 = __shfl(u, 32);
  float mx = fmaxf(s0, fmaxf(s1, s2));
  float e0 = __expf(s0-mx), e1 = __expf(s1-mx), e2 = __expf(s2-mx);
  float inv = 1.f / (e0 + e1 + e2);
  float w0 = e0*inv, w1 = e1*inv, w2v = e2*inv;
  float h0 = w0*mv00 + w1*mv10 + w2v*mv20;
  float h1 = w0*mv01 + w1*mv11 + w2v*mv21;

  // --- layer norm over 128 ---
  float sum = h0 + h1, sq = h0*h0 + h1*h1;
  #pragma unroll
  for (int m = 1; m < 64; m <<= 1){ sum += __shfl_xor(sum, m); sq += __shfl_xor(sq, m); }
  float mu = sum * (1.f/128.f);
  float var = sq * (1.f/128.f) - mu*mu;
  float rs = rsqrtf(var + LN_EPS);
  float2 gv = *(const float2*)(gamma + l*128 + f0);
  float2 bv = *(const float2*)(beta  + l*128 + f0);
  float y0 = fmaxf((h0 - mu)*rs*gv.x + bv.x, 0.f);
  float y1 = fmaxf((h1 - mu)*rs*gv.y + bv.y, 0.f);
  float xn0 = y0, xn1 = y1;
  if (l > 0){
    u32 xv = *(const u32*)(xb16 + (size_t)n*128 + f0);
    xn0 += bflo(xv); xn1 += bfhi(xv);
  }
  *(u32*)(xb16 + (size_t)n*128 + f0) = (u32)f2bf(xn0) | ((u32)f2bf(xn1) << 16);

  // fusion weight (softmax over 4 logits)
  float g0 = flog[0], g1 = flog[1], g2 = flog[2], g3 = flog[3];
  float gm = fmaxf(fmaxf(g0,g1), fmaxf(g2,g3));
  float q0 = __expf(g0-gm), q1 = __expf(g1-gm), q2 = __expf(g2-gm), q3 = __expf(g3-gm);
  float fwl = (l==0?q0 : l==1?q1 : l==2?q2 : q3) / (q0+q1+q2+q3);

  // classifier accumulate
  float4 w = *(const float4*)(clsW + lane*4);
  float o0 = xn0*w.x + xn1*w.z;
  float o1 = xn0*w.y + xn1*w.w;
  #pragma unroll
  for (int m = 1; m < 64; m <<= 1){ o0 += __shfl_xor(o0, m); o1 += __shfl_xor(o1, m); }
  if (lane == 0){
    float2* op = (float2*)(out + (size_t)n*2);
    float2 prev = (l > 0) ? *op : make_float2(0.f, 0.f);
    float r0 = prev.x + fwl*o0, r1 = prev.y + fwl*o1;
    if (l == LL-1){ r0 += clsB[0]; r1 += clsB[1]; }
    *op = make_float2(r0, r1);
  }
}

extern "C" void kernel_launch(void* const* d_in, const int* in_sizes, int n_in,
                              void* d_out, int out_size, void* d_ws, size_t ws_size,
                              hipStream_t stream){
  const float* X0    = (const float*)d_in[0];
  const int*   EI    = (const int*)d_in[1];
  const float* Wself = (const float*)d_in[2];
  const float* bs    = (const float*)d_in[3];
  const float* Wctx  = (const float*)d_in[4];
  const float* bc    = (const float*)d_in[5];
  const float* A1    = (const float*)d_in[6];
  const float* ab1   = (const float*)d_in[7];
  const float* aw2   = (const float*)d_in[8];
  const float* gam   = (const float*)d_in[9];
  const float* bet   = (const float*)d_in[10];
  const float* flog  = (const float*)d_in[11];
  const float* clsW  = (const float*)d_in[12];
  const float* clsB  = (const float*)d_in[13];
  float* out = (float*)d_out;

  char* wsp = (char*)d_ws;
  size_t o = 0;
  auto alloc = [&](size_t b)->char*{ char* p = wsp + o; o = (o + b + 255) & ~(size_t)255; return p; };
  u16*  xb16  = (u16*) alloc((size_t)N_NODES*128*2);
  u16*  S     = (u16*) alloc((size_t)N_NODES*128*2);
  u16*  P1    = (u16*) alloc((size_t)N_NODES*128*2);
  u16*  PdX   = (u16*) alloc((size_t)N_NODES*PDXW*2);
  u16*  SAb   = (u16*) alloc((size_t)N_NODES*16*2);
  u16*  P1A   = (u16*) alloc((size_t)N_NODES*16*2);
  u16*  WT    = (u16*) alloc((size_t)LL*NCOLS*128*2);
  float* bsA  = (float*)alloc(LL*16*4);
  float* bcA  = (float*)alloc(LL*16*4);
  int* bsum   = (int*) alloc((size_t)2*SCAN_NB*4);
  int* degO   = (int*) alloc((size_t)N_NODES*4);
  int* degI   = (int*) alloc((size_t)N_NODES*4);
  int* cursO  = (int*) alloc((size_t)N_NODES*4);
  int* cursI  = (int*) alloc((size_t)N_NODES*4);
  int* offO   = (int*) alloc((size_t)(N_NODES+1)*4);
  int* offI   = (int*) alloc((size_t)(N_NODES+1)*4);
  int* csrO   = (int*) alloc((size_t)N_EDGES*4);
  int* csrI   = (int*) alloc((size_t)N_EDGES*4);

  if (ws_size < o){
    k_fail<<<(N_NODES*2+255)/256, 256, 0, stream>>>(out);
    return;
  }

  (void)hipMemsetAsync(degO, 0, (size_t)((char*)offO - (char*)degO), stream);

  k_cvt_hist<<<(N_NODES*DD+255)/256, 256, 0, stream>>>(X0, xb16, EI, degO, degI);
  k_scan1<<<dim3(SCAN_NB,2), SCAN_B, 0, stream>>>(degO, degI, bsum);
  k_scan2<<<1, 64, 0, stream>>>(bsum, offO, offI);
  k_scan3<<<dim3(SCAN_NB,2), SCAN_B, 0, stream>>>(degO, degI, bsum, offO, offI);
  k_scatter<<<(N_EDGES+255)/256, 256, 0, stream>>>(EI, offO, offI, cursO, cursI, csrO, csrI);
  k_pack<<<WT_BLOCKS+1, 256, 0, stream>>>(Wself, Wctx, A1, bs, bc, WT, bsA, bcA);

  GemmOut go{S, P1, PdX, SAb, P1A};
  const int gemm_blocks = ((N_NODES/16) + 3) / 4;
  for (int l = 0; l < LL; ++l){
    k_gemm<<<gemm_blocks, 256, 0, stream>>>(xb16, WT + (size_t)l*NCOLS*128, go);
    k_aggepi<<<N_NODES/4, 256, 0, stream>>>(l, S, P1, PdX, SAb, P1A,
                                            offO, offI, csrO, csrI,
                                            bs, bc, bsA, bcA, ab1, aw2,
                                            gam, bet, flog, xb16,
                                            clsW, clsB, out);
  }
}

// Round 14
// 743.701 us; speedup vs baseline: 1.0172x; 1.0172x over previous
//
#include <hip/hip_runtime.h>

#define N_NODES 50000
#define N_EDGES 800000
#define DD 128
#define HH 128
#define LL 4
#define AHH 16
#define LN_EPS 1e-5f
#define NCOLS 432   // 128 S | 128 P1 | 128 Pd | 16 SA | 16 P1A | 16 PdA
#define PDXW 160    // PdX row: 128 Pd + 16 PdA + 16 pad (320B, line-aligned)
#define SCAN_B 512
#define SCAN_NB ((N_NODES + SCAN_B - 1) / SCAN_B)
#define WTPAD 136
#define WT_BLOCKS ((LL*NCOLS*DD)/256)   // 864, exact

typedef unsigned short u16;
typedef unsigned int u32;
typedef __attribute__((ext_vector_type(8))) short short8;
typedef __attribute__((ext_vector_type(4))) float f32x4;

__device__ __forceinline__ float bf2f(u16 h){
  u32 u = ((u32)h) << 16;
  return __builtin_bit_cast(float, u);
}
__device__ __forceinline__ float bflo(u32 v){ return __builtin_bit_cast(float, v << 16); }
__device__ __forceinline__ float bfhi(u32 v){ return __builtin_bit_cast(float, v & 0xffff0000u); }
__device__ __forceinline__ u16 f2bf(float x){
  u32 u = __builtin_bit_cast(u32, x);
  u += 0x7fffu + ((u >> 16) & 1u);
  return (u16)(u >> 16);
}

// ---------------- sentinel (workspace too small) ----------------
__global__ void k_fail(float* out){
  int i = blockIdx.x*256 + threadIdx.x;
  if (i < N_NODES*2) out[i] = 1.0e6f;
}

// ---------------- fused: f32->bf16 conversion + degree histograms ----------------
__global__ __launch_bounds__(256) void k_cvt_hist(const float* __restrict__ X,
    u16* __restrict__ Xb, const int* __restrict__ ei, int* degO, int* degI){
  int i = blockIdx.x*256 + threadIdx.x;
  if (i < N_NODES*DD) Xb[i] = f2bf(X[i]);
  if (i < N_EDGES){
    atomicAdd(&degO[ei[N_EDGES + i]], 1);  // tgt histogram (outgoing view)
    atomicAdd(&degI[ei[i]], 1);            // src histogram (incoming view)
  }
}

// 3-phase parallel exclusive scan
__global__ __launch_bounds__(SCAN_B) void k_scan1(const int* __restrict__ degO,
                                                  const int* __restrict__ degI, int* bsum){
  int b = blockIdx.x, t = threadIdx.x;
  const int* deg = blockIdx.y ? degI : degO;
  int i = b*SCAN_B + t;
  int v = (i < N_NODES) ? deg[i] : 0;
  #pragma unroll
  for (int m = 1; m < 64; m <<= 1) v += __shfl_xor(v, m);
  __shared__ int ws[SCAN_B/64];
  if ((t & 63) == 0) ws[t >> 6] = v;
  __syncthreads();
  if (t == 0){
    int s = 0;
    for (int w = 0; w < SCAN_B/64; ++w) s += ws[w];
    bsum[blockIdx.y*SCAN_NB + b] = s;
  }
}
__global__ void k_scan2(int* bsum, int* offO, int* offI){
  if (threadIdx.x == 0){
    int run = 0;
    for (int i = 0; i < SCAN_NB; ++i){ int v = bsum[i]; bsum[i] = run; run += v; }
    offO[N_NODES] = run;
    run = 0;
    for (int i = 0; i < SCAN_NB; ++i){ int v = bsum[SCAN_NB+i]; bsum[SCAN_NB+i] = run; run += v; }
    offI[N_NODES] = run;
  }
}
__global__ __launch_bounds__(SCAN_B) void k_scan3(const int* __restrict__ degO,
                                                  const int* __restrict__ degI,
                                                  const int* __restrict__ bsum,
                                                  int* offO, int* offI){
  int b = blockIdx.x, t = threadIdx.x, lane = t & 63, w = t >> 6;
  const int* deg = blockIdx.y ? degI : degO;
  int* off = blockIdx.y ? offI : offO;
  int i = b*SCAN_B + t;
  int v = (i < N_NODES) ? deg[i] : 0;
  int x = v;
  #pragma unroll
  for (int m = 1; m < 64; m <<= 1){ int tt = __shfl_up(x, m); if (lane >= m) x += tt; }
  __shared__ int ws[SCAN_B/64];
  if (lane == 63) ws[w] = x;
  __syncthreads();
  int woff = 0;
  for (int k = 0; k < w; ++k) woff += ws[k];
  if (i < N_NODES) off[i] = bsum[blockIdx.y*SCAN_NB + b] + woff + x - v;
}

__global__ void k_scatter(const int* __restrict__ ei, const int* __restrict__ offO,
                          const int* __restrict__ offI, int* cursO, int* cursI,
                          int* csrO, int* csrI){
  int e = blockIdx.x*256 + threadIdx.x;
  if (e >= N_EDGES) return;
  int s = ei[e], t = ei[N_EDGES + e];
  int p = atomicAdd(&cursO[t], 1); csrO[offO[t] + p] = s;
  int q = atomicAdd(&cursI[s], 1); csrI[offI[s] + q] = t;
}

// ---------------- fused weight+bias packing (f32 sources -> bf16 WT, f32 bsA/bcA) ----------------
__global__ void k_pack(const float* __restrict__ Wself, const float* __restrict__ Wctx,
                       const float* __restrict__ A1, const float* __restrict__ bs,
                       const float* __restrict__ bc, u16* __restrict__ WT,
                       float* bsA, float* bcA){
  if (blockIdx.x == WT_BLOCKS){
    int i = threadIdx.x;
    if (i < LL*2*AHH){
      int l = i >> 5, which = (i >> 4) & 1, a = i & 15;
      const float* b = which ? (bc + l*HH) : (bs + l*HH);
      const float* A = A1 + (size_t)l*HH*AHH;
      float v = 0.f;
      for (int h = 0; h < HH; ++h) v += b[h] * A[h*AHH + a];
      (which ? bcA : bsA)[l*AHH + a] = v;
    }
    return;
  }
  int idx = blockIdx.x*256 + threadIdx.x;
  int k = idx & 127;
  int j = (idx >> 7) % NCOLS;
  int l = idx / (NCOLS*DD);
  const float* Ws = Wself + (size_t)l*DD*HH;
  const float* Wc = Wctx + (size_t)l*2*DD*HH;
  const float* A  = A1 + (size_t)l*HH*AHH;
  float v = 0.f;
  if (j < 128) v = Ws[k*HH + j];
  else if (j < 256) v = Wc[k*HH + (j-128)];
  else if (j < 384) v = Wc[(128+k)*HH + (j-256)] - Wc[k*HH + (j-256)];
  else if (j < 400){ int a = j-384; for (int h=0; h<HH; ++h) v += Ws[k*HH+h] * A[h*AHH+a]; }
  else if (j < 416){ int a = j-400; for (int h=0; h<HH; ++h) v += Wc[k*HH+h] * A[h*AHH+a]; }
  else { int a = j-416; for (int h=0; h<HH; ++h) v += (Wc[(128+k)*HH+h] - Wc[k*HH+h]) * A[h*AHH+a]; }
  WT[((size_t)l*NCOLS + j)*DD + k] = f2bf(v);
}

// ---------------- fused GEMM: 3-tile LDS staging, 9 stages ----------------
struct GemmOut { u16 *S, *P1, *PdX, *SA, *P1A; };

__global__ __launch_bounds__(256) void k_gemm(const u16* __restrict__ X,
                                              const u16* __restrict__ WT, GemmOut o){
  __shared__ u16 lw[3*16*WTPAD];
  int tid = threadIdx.x;
  int wid = tid >> 6, lane = tid & 63;
  int m0 = (blockIdx.x*4 + wid)*16;
  bool mvalid = (m0 < N_NODES);
  int m0c = mvalid ? m0 : (N_NODES - 16);
  int l15 = lane & 15, quad = lane >> 4;
  int sr = tid >> 4, sp = tid & 15;

  f32x4 acc[27];
  #pragma unroll
  for (int j = 0; j < 27; ++j) acc[j] = (f32x4){0.f,0.f,0.f,0.f};

  const u16* xr = X + (size_t)(m0c + l15)*DD + quad*8;
  short8 a[4];
  #pragma unroll
  for (int ks = 0; ks < 4; ++ks) a[ks] = *(const short8*)(xr + ks*32);

  short8 st[3];
  #pragma unroll
  for (int k = 0; k < 3; ++k)
    st[k] = *(const short8*)(WT + ((size_t)k*16 + sr)*DD + sp*8);

  for (int stage = 0; stage < 9; ++stage){
    int jbase = stage*3;
    __syncthreads();
    #pragma unroll
    for (int k = 0; k < 3; ++k)
      *(short8*)(&lw[(k*16 + sr)*WTPAD + sp*8]) = st[k];
    __syncthreads();
    if (stage < 8){
      #pragma unroll
      for (int k = 0; k < 3; ++k)
        st[k] = *(const short8*)(WT + ((size_t)(jbase+3+k)*16 + sr)*DD + sp*8);
    }
    #pragma unroll
    for (int k = 0; k < 3; ++k){
      const u16* wb = &lw[(k*16 + l15)*WTPAD + quad*8];
      #pragma unroll
      for (int ks = 0; ks < 4; ++ks){
        short8 b = *(const short8*)(wb + ks*32);
        acc[jbase+k] = __builtin_amdgcn_mfma_f32_16x16x32_bf16(a[ks], b, acc[jbase+k], 0, 0, 0);
      }
    }
  }
  if (!mvalid) return;
  #pragma unroll
  for (int j = 0; j < 27; ++j){
    int col = j*16 + l15;
    #pragma unroll
    for (int r = 0; r < 4; ++r){
      int row = m0 + quad*4 + r;
      u16 hv = f2bf(acc[j][r]);
      if (col < 128)      o.S  [(size_t)row*128 + col]        = hv;
      else if (col < 256) o.P1 [(size_t)row*128 + col - 128]  = hv;
      else if (col < 384) o.PdX[(size_t)row*PDXW + col - 256] = hv;
      else if (col < 400) o.SA [(size_t)row*16  + col - 384]  = hv;
      else if (col < 416) o.P1A[(size_t)row*16  + col - 400]  = hv;
      else                o.PdX[(size_t)row*PDXW + 128 + (col - 416)] = hv;
    }
  }
}

// ------- fused CSR gather (single pass over PdX rows: Pd + PdA together) -------
__global__ __launch_bounds__(256) void k_aggepi(int l,
  const u16* __restrict__ S, const u16* __restrict__ P1,
  const u16* __restrict__ PdX, const u16* __restrict__ SA,
  const u16* __restrict__ P1A,
  const int* __restrict__ offO, const int* __restrict__ offI,
  const int* __restrict__ csrO, const int* __restrict__ csrI,
  const float* __restrict__ b_self, const float* __restrict__ b_ctx,
  const float* __restrict__ bsA, const float* __restrict__ bcA,
  const float* __restrict__ att_b1, const float* __restrict__ att_w2,
  const float* __restrict__ gamma, const float* __restrict__ beta,
  const float* __restrict__ flog,
  u16* __restrict__ xb16,
  const float* __restrict__ clsW, const float* __restrict__ clsB,
  float* __restrict__ out)
{
  int n = (blockIdx.x * 256 + threadIdx.x) >> 6;
  int lane = threadIdx.x & 63;
  int f0 = lane * 2;
  const u16* PdF  = PdX + f0;                    // main: u32 @ PdF + nb*PDXW (2 feats/lane)
  const u16* PdAF = PdX + 128 + (lane & 7)*2;    // aux: u32 @ PdAF + nb*PDXW (PdA pair, replicated x8)

  int begO = offO[n], endO = offO[n+1];
  int begI = offI[n], endI = offI[n+1];

  float o00=0.f,o01=0.f,o10=0.f,o11=0.f,o20=0.f,o21=0.f,o30=0.f,o31=0.f;
  float i00=0.f,i01=0.f,i10=0.f,i11=0.f,i20=0.f,i21=0.f,i30=0.f,i31=0.f;
  float poa0=0.f, poa1=0.f, pia0=0.f, pia1=0.f;  // PdA pair sums (feat 2p, 2p+1), p = lane&7

  int eO = begO, eI = begI;
  // alignment heads (csr bases 256B-aligned)
  for (; eO < endO && (eO & 3); ++eO){
    size_t rb = (size_t)csrO[eO]*PDXW;
    u32 v = *(const u32*)(PdF + rb);
    u32 p = *(const u32*)(PdAF + rb);
    o00 += bflo(v); o01 += bfhi(v);
    poa0 += bflo(p); poa1 += bfhi(p);
  }
  for (; eI < endI && (eI & 3); ++eI){
    size_t rb = (size_t)csrI[eI]*PDXW;
    u32 v = *(const u32*)(PdF + rb);
    u32 p = *(const u32*)(PdAF + rb);
    i00 += bflo(v); i01 += bfhi(v);
    pia0 += bflo(p); pia1 += bfhi(p);
  }
  // fused main loop: 4 O + 4 I rows (+aux) in flight, int4 index loads
  for (; eO + 4 <= endO && eI + 4 <= endI; eO += 4, eI += 4){
    int4 nO = *(const int4*)(csrO + eO);
    int4 nI = *(const int4*)(csrI + eI);
    size_t rO0 = (size_t)nO.x*PDXW, rO1 = (size_t)nO.y*PDXW, rO2 = (size_t)nO.z*PDXW, rO3 = (size_t)nO.w*PDXW;
    size_t rI0 = (size_t)nI.x*PDXW, rI1 = (size_t)nI.y*PDXW, rI2 = (size_t)nI.z*PDXW, rI3 = (size_t)nI.w*PDXW;
    u32 a0 = *(const u32*)(PdF + rO0);
    u32 a1 = *(const u32*)(PdF + rO1);
    u32 a2 = *(const u32*)(PdF + rO2);
    u32 a3 = *(const u32*)(PdF + rO3);
    u32 b0 = *(const u32*)(PdF + rI0);
    u32 b1 = *(const u32*)(PdF + rI1);
    u32 b2 = *(const u32*)(PdF + rI2);
    u32 b3 = *(const u32*)(PdF + rI3);
    u32 pa0 = *(const u32*)(PdAF + rO0);
    u32 pa1 = *(const u32*)(PdAF + rO1);
    u32 pa2 = *(const u32*)(PdAF + rO2);
    u32 pa3 = *(const u32*)(PdAF + rO3);
    u32 pb0 = *(const u32*)(PdAF + rI0);
    u32 pb1 = *(const u32*)(PdAF + rI1);
    u32 pb2 = *(const u32*)(PdAF + rI2);
    u32 pb3 = *(const u32*)(PdAF + rI3);
    o00 += bflo(a0); o01 += bfhi(a0);
    o10 += bflo(a1); o11 += bfhi(a1);
    o20 += bflo(a2); o21 += bfhi(a2);
    o30 += bflo(a3); o31 += bfhi(a3);
    i00 += bflo(b0); i01 += bfhi(b0);
    i10 += bflo(b1); i11 += bfhi(b1);
    i20 += bflo(b2); i21 += bfhi(b2);
    i30 += bflo(b3); i31 += bfhi(b3);
    poa0 += bflo(pa0) + bflo(pa1) + bflo(pa2) + bflo(pa3);
    poa1 += bfhi(pa0) + bfhi(pa1) + bfhi(pa2) + bfhi(pa3);
    pia0 += bflo(pb0) + bflo(pb1) + bflo(pb2) + bflo(pb3);
    pia1 += bfhi(pb0) + bfhi(pb1) + bfhi(pb2) + bfhi(pb3);
  }
  // drain O
  for (; eO + 4 <= endO; eO += 4){
    int4 nO = *(const int4*)(csrO + eO);
    size_t rO0 = (size_t)nO.x*PDXW, rO1 = (size_t)nO.y*PDXW, rO2 = (size_t)nO.z*PDXW, rO3 = (size_t)nO.w*PDXW;
    u32 a0 = *(const u32*)(PdF + rO0);
    u32 a1 = *(const u32*)(PdF + rO1);
    u32 a2 = *(const u32*)(PdF + rO2);
    u32 a3 = *(const u32*)(PdF + rO3);
    u32 pa0 = *(const u32*)(PdAF + rO0);
    u32 pa1 = *(const u32*)(PdAF + rO1);
    u32 pa2 = *(const u32*)(PdAF + rO2);
    u32 pa3 = *(const u32*)(PdAF + rO3);
    o00 += bflo(a0); o01 += bfhi(a0);
    o10 += bflo(a1); o11 += bfhi(a1);
    o20 += bflo(a2); o21 += bfhi(a2);
    o30 += bflo(a3); o31 += bfhi(a3);
    poa0 += bflo(pa0) + bflo(pa1) + bflo(pa2) + bflo(pa3);
    poa1 += bfhi(pa0) + bfhi(pa1) + bfhi(pa2) + bfhi(pa3);
  }
  for (; eO < endO; ++eO){
    size_t rb = (size_t)csrO[eO]*PDXW;
    u32 v = *(const u32*)(PdF + rb);
    u32 p = *(const u32*)(PdAF + rb);
    o00 += bflo(v); o01 += bfhi(v);
    poa0 += bflo(p); poa1 += bfhi(p);
  }
  // drain I
  for (; eI + 4 <= endI; eI += 4){
    int4 nI = *(const int4*)(csrI + eI);
    size_t rI0 = (size_t)nI.x*PDXW, rI1 = (size_t)nI.y*PDXW, rI2 = (size_t)nI.z*PDXW, rI3 = (size_t)nI.w*PDXW;
    u32 b0 = *(const u32*)(PdF + rI0);
    u32 b1 = *(const u32*)(PdF + rI1);
    u32 b2 = *(const u32*)(PdF + rI2);
    u32 b3 = *(const u32*)(PdF + rI3);
    u32 pb0 = *(const u32*)(PdAF + rI0);
    u32 pb1 = *(const u32*)(PdAF + rI1);
    u32 pb2 = *(const u32*)(PdAF + rI2);
    u32 pb3 = *(const u32*)(PdAF + rI3);
    i00 += bflo(b0); i01 += bfhi(b0);
    i10 += bflo(b1); i11 += bfhi(b1);
    i20 += bflo(b2); i21 += bfhi(b2);
    i30 += bflo(b3); i31 += bfhi(b3);
    pia0 += bflo(pb0) + bflo(pb1) + bflo(pb2) + bflo(pb3);
    pia1 += bfhi(pb0) + bfhi(pb1) + bfhi(pb2) + bfhi(pb3);
  }
  for (; eI < endI; ++eI){
    size_t rb = (size_t)csrI[eI]*PDXW;
    u32 v = *(const u32*)(PdF + rb);
    u32 p = *(const u32*)(PdAF + rb);
    i00 += bflo(v); i01 += bfhi(v);
    pia0 += bflo(p); pia1 += bfhi(p);
  }
  float ao0 = (o00+o10)+(o20+o30), ao1 = (o01+o11)+(o21+o31);
  float ai0 = (i00+i10)+(i20+i30), ai1 = (i01+i11)+(i21+i31);

  // PdA sums: lane k holds pair (k&7) = feats 2(k&7), 2(k&7)+1 — replicated 8x.
  int a16 = lane & 15, g = lane >> 4;
  float aoa, aia;
  {
    int p = a16 >> 1;
    float t0 = __shfl(poa0, p), t1 = __shfl(poa1, p);
    float u0 = __shfl(pia0, p), u1 = __shfl(pia1, p);
    int odd = a16 & 1;
    aoa = odd ? t1 : t0;
    aia = odd ? u1 : u0;
  }

  float dO = (float)(endO - begO), dI = (float)(endI - begI);

  // --- three views, 2 features per lane ---
  u32 sv = *(const u32*)(S  + (size_t)n*128 + f0);
  u32 pv = *(const u32*)(P1 + (size_t)n*128 + f0);
  float2 bsv = *(const float2*)(b_self + l*128 + f0);
  float2 bcv = *(const float2*)(b_ctx  + l*128 + f0);
  float p10 = bflo(pv), p11 = bfhi(pv);
  float mv00 = bflo(sv) + bsv.x;
  float mv01 = bfhi(sv) + bsv.y;
  float mv10 = dO*p10 + ao0 + bcv.x, mv11 = dO*p11 + ao1 + bcv.y;
  float mv20 = dI*p10 + ai0 + bcv.x, mv21 = dI*p11 + ai1 + bcv.y;

  // --- attention: lanes [v*16 + a], v<3 compute tanh(t + b1)*w2, reduce over a ---
  int a = a16, v = g;
  float u = 0.f;
  if (v < 3){
    float t;
    if (v == 0)      t = bf2f(SA[(size_t)n*16 + a]) + bsA[l*16 + a];
    else if (v == 1) t = dO*bf2f(P1A[(size_t)n*16 + a]) + aoa + bcA[l*16 + a];
    else             t = dI*bf2f(P1A[(size_t)n*16 + a]) + aia + bcA[l*16 + a];
    u = tanhf(t + att_b1[l*16 + a]) * att_w2[l*16 + a];
  }
  u += __shfl_xor(u, 1); u += __shfl_xor(u, 2);
  u += __shfl_xor(u, 4); u += __shfl_xor(u, 8);
  float s0 = __shfl(u, 0), s1 = __shfl(u, 16), s2 = __shfl(u, 32);
  float mx = fmaxf(s0, fmaxf(s1, s2));
  float e0 = __expf(s0-mx), e1 = __expf(s1-mx), e2 = __expf(s2-mx);
  float inv = 1.f / (e0 + e1 + e2);
  float w0 = e0*inv, w1 = e1*inv, w2v = e2*inv;
  float h0 = w0*mv00 + w1*mv10 + w2v*mv20;
  float h1 = w0*mv01 + w1*mv11 + w2v*mv21;

  // --- layer norm over 128 ---
  float sum = h0 + h1, sq = h0*h0 + h1*h1;
  #pragma unroll
  for (int m = 1; m < 64; m <<= 1){ sum += __shfl_xor(sum, m); sq += __shfl_xor(sq, m); }
  float mu = sum * (1.f/128.f);
  float var = sq * (1.f/128.f) - mu*mu;
  float rs = rsqrtf(var + LN_EPS);
  float2 gv = *(const float2*)(gamma + l*128 + f0);
  float2 bv = *(const float2*)(beta  + l*128 + f0);
  float y0 = fmaxf((h0 - mu)*rs*gv.x + bv.x, 0.f);
  float y1 = fmaxf((h1 - mu)*rs*gv.y + bv.y, 0.f);
  float xn0 = y0, xn1 = y1;
  if (l > 0){
    u32 xv = *(const u32*)(xb16 + (size_t)n*128 + f0);
    xn0 += bflo(xv); xn1 += bfhi(xv);
  }
  *(u32*)(xb16 + (size_t)n*128 + f0) = (u32)f2bf(xn0) | ((u32)f2bf(xn1) << 16);

  // fusion weight (softmax over 4 logits)
  float g0 = flog[0], g1 = flog[1], g2 = flog[2], g3 = flog[3];
  float gm = fmaxf(fmaxf(g0,g1), fmaxf(g2,g3));
  float q0 = __expf(g0-gm), q1 = __expf(g1-gm), q2 = __expf(g2-gm), q3 = __expf(g3-gm);
  float fwl = (l==0?q0 : l==1?q1 : l==2?q2 : q3) / (q0+q1+q2+q3);

  // classifier accumulate
  float4 w = *(const float4*)(clsW + lane*4);
  float o0 = xn0*w.x + xn1*w.z;
  float o1 = xn0*w.y + xn1*w.w;
  #pragma unroll
  for (int m = 1; m < 64; m <<= 1){ o0 += __shfl_xor(o0, m); o1 += __shfl_xor(o1, m); }
  if (lane == 0){
    float2* op = (float2*)(out + (size_t)n*2);
    float2 prev = (l > 0) ? *op : make_float2(0.f, 0.f);
    float r0 = prev.x + fwl*o0, r1 = prev.y + fwl*o1;
    if (l == LL-1){ r0 += clsB[0]; r1 += clsB[1]; }
    *op = make_float2(r0, r1);
  }
}

extern "C" void kernel_launch(void* const* d_in, const int* in_sizes, int n_in,
                              void* d_out, int out_size, void* d_ws, size_t ws_size,
                              hipStream_t stream){
  const float* X0    = (const float*)d_in[0];
  const int*   EI    = (const int*)d_in[1];
  const float* Wself = (const float*)d_in[2];
  const float* bs    = (const float*)d_in[3];
  const float* Wctx  = (const float*)d_in[4];
  const float* bc    = (const float*)d_in[5];
  const float* A1    = (const float*)d_in[6];
  const float* ab1   = (const float*)d_in[7];
  const float* aw2   = (const float*)d_in[8];
  const float* gam   = (const float*)d_in[9];
  const float* bet   = (const float*)d_in[10];
  const float* flog  = (const float*)d_in[11];
  const float* clsW  = (const float*)d_in[12];
  const float* clsB  = (const float*)d_in[13];
  float* out = (float*)d_out;

  char* wsp = (char*)d_ws;
  size_t o = 0;
  auto alloc = [&](size_t b)->char*{ char* p = wsp + o; o = (o + b + 255) & ~(size_t)255; return p; };
  u16*  xb16  = (u16*) alloc((size_t)N_NODES*128*2);
  u16*  S     = (u16*) alloc((size_t)N_NODES*128*2);
  u16*  P1    = (u16*) alloc((size_t)N_NODES*128*2);
  u16*  PdX   = (u16*) alloc((size_t)N_NODES*PDXW*2);
  u16*  SAb   = (u16*) alloc((size_t)N_NODES*16*2);
  u16*  P1A   = (u16*) alloc((size_t)N_NODES*16*2);
  u16*  WT    = (u16*) alloc((size_t)LL*NCOLS*128*2);
  float* bsA  = (float*)alloc(LL*16*4);
  float* bcA  = (float*)alloc(LL*16*4);
  int* bsum   = (int*) alloc((size_t)2*SCAN_NB*4);
  int* degO   = (int*) alloc((size_t)N_NODES*4);
  int* degI   = (int*) alloc((size_t)N_NODES*4);
  int* cursO  = (int*) alloc((size_t)N_NODES*4);
  int* cursI  = (int*) alloc((size_t)N_NODES*4);
  int* offO   = (int*) alloc((size_t)(N_NODES+1)*4);
  int* offI   = (int*) alloc((size_t)(N_NODES+1)*4);
  int* csrO   = (int*) alloc((size_t)N_EDGES*4);
  int* csrI   = (int*) alloc((size_t)N_EDGES*4);

  if (ws_size < o){
    k_fail<<<(N_NODES*2+255)/256, 256, 0, stream>>>(out);
    return;
  }

  (void)hipMemsetAsync(degO, 0, (size_t)((char*)offO - (char*)degO), stream);

  k_cvt_hist<<<(N_NODES*DD+255)/256, 256, 0, stream>>>(X0, xb16, EI, degO, degI);
  k_scan1<<<dim3(SCAN_NB,2), SCAN_B, 0, stream>>>(degO, degI, bsum);
  k_scan2<<<1, 64, 0, stream>>>(bsum, offO, offI);
  k_scan3<<<dim3(SCAN_NB,2), SCAN_B, 0, stream>>>(degO, degI, bsum, offO, offI);
  k_scatter<<<(N_EDGES+255)/256, 256, 0, stream>>>(EI, offO, offI, cursO, cursI, csrO, csrI);
  k_pack<<<WT_BLOCKS+1, 256, 0, stream>>>(Wself, Wctx, A1, bs, bc, WT, bsA, bcA);

  GemmOut go{S, P1, PdX, SAb, P1A};
  const int gemm_blocks = ((N_NODES/16) + 3) / 4;
  for (int l = 0; l < LL; ++l){
    k_gemm<<<gemm_blocks, 256, 0, stream>>>(xb16, WT + (size_t)l*NCOLS*128, go);
    k_aggepi<<<N_NODES/4, 256, 0, stream>>>(l, S, P1, PdX, SAb, P1A,
                                            offO, offI, csrO, csrI,
                                            bs, bc, bsA, bcA, ab1, aw2,
                                            gam, bet, flog, xb16,
                                            clsW, clsB, out);
  }
}